// Round 1
// baseline (1416.335 us; speedup 1.0000x reference)
//
#include <hip/hip_runtime.h>
#include <cstdint>

#define HIDDEN 4096
#define INTER 11008
#define KACT 3302
#define KPAD 3328   // 26*128, zero-padded active dimension
#define TOKENS 8192

#define BM 128
#define BN 128
#define BK 64

typedef __bf16 bf16x8 __attribute__((ext_vector_type(8)));
typedef float floatx4 __attribute__((ext_vector_type(4)));

// round-to-nearest-even f32 -> bf16
__device__ __forceinline__ unsigned short f2b(float f) {
  union { float f; unsigned u; } c; c.f = f;
  unsigned r = (c.u + 0x7fffu + ((c.u >> 16) & 1u)) >> 16;
  return (unsigned short)r;
}

// async global->LDS, 16B per lane; lds base must be wave-uniform (lane i lands at base + i*16B)
__device__ __forceinline__ void async16(const unsigned short* g, unsigned short* l) {
  __builtin_amdgcn_global_load_lds(
      (const __attribute__((address_space(1))) void*)g,
      (__attribute__((address_space(3))) void*)l, 16, 0, 0);
}

// ---------------- convert / gather kernels ----------------

__global__ void cvt_x(const float* __restrict__ x, unsigned short* __restrict__ o) {
  long i = ((long)blockIdx.x * blockDim.x + threadIdx.x) * 4;
  float4 v = *(const float4*)(x + i);
  ushort4 b;
  b.x = f2b(v.x); b.y = f2b(v.y); b.z = f2b(v.z); b.w = f2b(v.w);
  *(ushort4*)(o + i) = b;
}

// o[row][:] = bf16(W[idx[row]][:]) for row < KACT, else zeros.  grid = KPAD, block = 256
__global__ void cvt_gather_rows(const float* __restrict__ W, const int* __restrict__ idx,
                                unsigned short* __restrict__ o) {
  int row = blockIdx.x;
  int src = (row < KACT) ? idx[row] : -1;
  unsigned short* orow = o + (long)row * HIDDEN;
  if (src >= 0) {
    const float* srow = W + (long)src * HIDDEN;
    for (int c = threadIdx.x * 4; c < HIDDEN; c += blockDim.x * 4) {
      float4 v = *(const float4*)(srow + c);
      ushort4 b; b.x = f2b(v.x); b.y = f2b(v.y); b.z = f2b(v.z); b.w = f2b(v.w);
      *(ushort4*)(orow + c) = b;
    }
  } else {
    for (int c = threadIdx.x * 4; c < HIDDEN; c += blockDim.x * 4) {
      ushort4 b = {0, 0, 0, 0};
      *(ushort4*)(orow + c) = b;
    }
  }
}

// o[h][j] = bf16(W[h][idx[j]]) for j < KACT, else 0.  grid = HIDDEN, block = 256
__global__ void cvt_gather_cols(const float* __restrict__ W, const int* __restrict__ idx,
                                unsigned short* __restrict__ o) {
  int h = blockIdx.x;
  const float* wrow = W + (long)h * INTER;
  unsigned short* orow = o + (long)h * KPAD;
  for (int j = threadIdx.x; j < KPAD; j += blockDim.x) {
    unsigned short v = 0;
    if (j < KACT) v = f2b(wrow[idx[j]]);
    orow[j] = v;
  }
}

// ---------------- fused gate+up GEMM ----------------
// A: Xb [TOKENS, HIDDEN] bf16;  Bg/Bu: [KPAD, HIDDEN] bf16 (B^T layout)
// H:  [TOKENS, KPAD] bf16 = silu(A.Bg^T) * (A.Bu^T)
__global__ __launch_bounds__(256, 2) void gateup_kernel(
    const unsigned short* __restrict__ A,
    const unsigned short* __restrict__ Bg,
    const unsigned short* __restrict__ Bu,
    unsigned short* __restrict__ H) {
  __shared__ unsigned short As[BM * BK];
  __shared__ unsigned short Bgs[BN * BK];
  __shared__ unsigned short Bus[BN * BK];

  const int tid = threadIdx.x;
  const int wave = tid >> 6;
  const int lane = tid & 63;
  const int wm = wave >> 1, wn = wave & 1;
  const int tileM = blockIdx.x * BM;
  const int tileN = blockIdx.y * BN;

  const int srow = tid >> 3;        // staging row within 32-row round
  const int scol = (tid & 7) * 8;   // staging col offset (elements)

  floatx4 zero = {0.f, 0.f, 0.f, 0.f};
  floatx4 accG[4][4], accU[4][4];
  for (int i = 0; i < 4; ++i)
    for (int j = 0; j < 4; ++j) { accG[i][j] = zero; accU[i][j] = zero; }

  const int fr = lane & 15;  // fragment row (A/B) / output col
  const int fq = lane >> 4;  // quad

  for (int k0 = 0; k0 < HIDDEN; k0 += BK) {
#pragma unroll
    for (int r = 0; r < 4; ++r) {
      async16(A  + (long)(tileM + r * 32 + srow) * HIDDEN + k0 + scol, As  + r * 2048 + wave * 512);
      async16(Bg + (long)(tileN + r * 32 + srow) * HIDDEN + k0 + scol, Bgs + r * 2048 + wave * 512);
      async16(Bu + (long)(tileN + r * 32 + srow) * HIDDEN + k0 + scol, Bus + r * 2048 + wave * 512);
    }
    __syncthreads();
#pragma unroll
    for (int ks = 0; ks < BK; ks += 32) {
      bf16x8 af[4], bgf[4], buf_[4];
#pragma unroll
      for (int i = 0; i < 4; ++i)
        af[i] = *(const bf16x8*)(As + (wm * 64 + i * 16 + fr) * BK + ks + fq * 8);
#pragma unroll
      for (int j = 0; j < 4; ++j) {
        bgf[j]  = *(const bf16x8*)(Bgs + (wn * 64 + j * 16 + fr) * BK + ks + fq * 8);
        buf_[j] = *(const bf16x8*)(Bus + (wn * 64 + j * 16 + fr) * BK + ks + fq * 8);
      }
#pragma unroll
      for (int i = 0; i < 4; ++i)
#pragma unroll
        for (int j = 0; j < 4; ++j) {
          accG[i][j] = __builtin_amdgcn_mfma_f32_16x16x32_bf16(af[i], bgf[j],  accG[i][j], 0, 0, 0);
          accU[i][j] = __builtin_amdgcn_mfma_f32_16x16x32_bf16(af[i], buf_[j], accU[i][j], 0, 0, 0);
        }
    }
    __syncthreads();
  }

  // epilogue: h = silu(g)*u -> bf16.  C/D layout: col=lane&15, row=(lane>>4)*4+reg
#pragma unroll
  for (int i = 0; i < 4; ++i)
#pragma unroll
    for (int j = 0; j < 4; ++j)
#pragma unroll
      for (int r = 0; r < 4; ++r) {
        float g = accG[i][j][r];
        float u = accU[i][j][r];
        float h = (g / (1.f + __expf(-g))) * u;
        int row = tileM + wm * 64 + i * 16 + fq * 4 + r;
        int col = tileN + wn * 64 + j * 16 + fr;
        H[(long)row * KPAD + col] = f2b(h);
      }
}

// ---------------- down GEMM ----------------
// A: H [TOKENS, KPAD] bf16;  B: Wdb [HIDDEN, KPAD] bf16 (B^T layout);  C: [TOKENS, HIDDEN] f32
__global__ __launch_bounds__(256) void down_kernel(
    const unsigned short* __restrict__ A,
    const unsigned short* __restrict__ B,
    float* __restrict__ C) {
  __shared__ unsigned short As[BM * BK];
  __shared__ unsigned short Bs[BN * BK];

  const int tid = threadIdx.x;
  const int wave = tid >> 6;
  const int lane = tid & 63;
  const int wm = wave >> 1, wn = wave & 1;
  const int tileM = blockIdx.x * BM;
  const int tileN = blockIdx.y * BN;

  const int srow = tid >> 3;
  const int scol = (tid & 7) * 8;

  floatx4 zero = {0.f, 0.f, 0.f, 0.f};
  floatx4 acc[4][4];
  for (int i = 0; i < 4; ++i)
    for (int j = 0; j < 4; ++j) acc[i][j] = zero;

  const int fr = lane & 15;
  const int fq = lane >> 4;

  for (int k0 = 0; k0 < KPAD; k0 += BK) {
#pragma unroll
    for (int r = 0; r < 4; ++r) {
      async16(A + (long)(tileM + r * 32 + srow) * KPAD + k0 + scol, As + r * 2048 + wave * 512);
      async16(B + (long)(tileN + r * 32 + srow) * KPAD + k0 + scol, Bs + r * 2048 + wave * 512);
    }
    __syncthreads();
#pragma unroll
    for (int ks = 0; ks < BK; ks += 32) {
      bf16x8 af[4], bf_[4];
#pragma unroll
      for (int i = 0; i < 4; ++i)
        af[i] = *(const bf16x8*)(As + (wm * 64 + i * 16 + fr) * BK + ks + fq * 8);
#pragma unroll
      for (int j = 0; j < 4; ++j)
        bf_[j] = *(const bf16x8*)(Bs + (wn * 64 + j * 16 + fr) * BK + ks + fq * 8);
#pragma unroll
      for (int i = 0; i < 4; ++i)
#pragma unroll
        for (int j = 0; j < 4; ++j)
          acc[i][j] = __builtin_amdgcn_mfma_f32_16x16x32_bf16(af[i], bf_[j], acc[i][j], 0, 0, 0);
    }
    __syncthreads();
  }

#pragma unroll
  for (int i = 0; i < 4; ++i)
#pragma unroll
    for (int j = 0; j < 4; ++j)
#pragma unroll
      for (int r = 0; r < 4; ++r) {
        int row = tileM + wm * 64 + i * 16 + fq * 4 + r;
        int col = tileN + wn * 64 + j * 16 + fr;
        C[(long)row * HIDDEN + col] = acc[i][j][r];
      }
}

// ---------------- launch ----------------

extern "C" void kernel_launch(void* const* d_in, const int* in_sizes, int n_in,
                              void* d_out, int out_size, void* d_ws, size_t ws_size,
                              hipStream_t stream) {
  const float* x  = (const float*)d_in[0];
  const float* Wg = (const float*)d_in[1];
  const float* Wu = (const float*)d_in[2];
  const float* Wd = (const float*)d_in[3];
  const int* idx  = (const int*)d_in[4];
  float* out = (float*)d_out;

  char* ws = (char*)d_ws;
  unsigned short* Xb  = (unsigned short*)ws; ws += (size_t)TOKENS * HIDDEN * 2;
  unsigned short* Wgb = (unsigned short*)ws; ws += (size_t)KPAD * HIDDEN * 2;
  unsigned short* Wub = (unsigned short*)ws; ws += (size_t)KPAD * HIDDEN * 2;
  unsigned short* Wdb = (unsigned short*)ws; ws += (size_t)HIDDEN * KPAD * 2;
  unsigned short* Hb  = (unsigned short*)ws; ws += (size_t)TOKENS * KPAD * 2;

  cvt_x<<<(TOKENS * HIDDEN) / 1024, 256, 0, stream>>>(x, Xb);
  cvt_gather_rows<<<KPAD, 256, 0, stream>>>(Wg, idx, Wgb);
  cvt_gather_rows<<<KPAD, 256, 0, stream>>>(Wu, idx, Wub);
  cvt_gather_cols<<<HIDDEN, 256, 0, stream>>>(Wd, idx, Wdb);
  gateup_kernel<<<dim3(TOKENS / BM, KPAD / BN), 256, 0, stream>>>(Xb, Wgb, Wub, Hb);
  down_kernel<<<dim3(TOKENS / BM, HIDDEN / BN), 256, 0, stream>>>(Hb, Wdb, out);
}